// Round 3
// baseline (77.302 us; speedup 1.0000x reference)
//
#include <hip/hip_runtime.h>

// HiPPO-LegS reconstruction: out = sum_{i=1..256} coef[i-1]*sqrt(2i+1)*P_i(x),
// x = 2t/curr_t - 1.
//
// R2 post-mortem: dur_us invariant at ~68 across two very different kernels ->
// ~42us of it is harness re-poison (268MB fill @40.5us + restores); kernel
// itself ~26us, limited by 2 waves/SIMD occupancy + per-iter LDS-pipe cost.
//
// R3: 1 elem/thread (2048 blocks -> 8 waves/SIMD, full occupancy), constants
// moved off the LDS/VALU pipes entirely: pre-kernel builds a global table,
// main loop reads it via readfirstlane-forced uniform index -> s_load on the
// scalar pipe.
//
// Rescaled recurrence (3 VALU/degree):
//   S_d = P_d/g_d, g_{d+1} = g_d*(2d+1)/(2d+2), g_0=2, g_1=1
//   S_{d+1} = (2x)*S_d - beta_d*S_{d-1}, beta_d = 4d^2/(4d^2-1)
//   out = sum_i w'_i*S_i, w'_i = coef[i-1]*sqrt(2i+1)*g_i, g_i = 2*C(2i,i)/4^i

#define NPAIR 128  // pair-iters cover degrees 2..257 (257's weight = 0)

__device__ __forceinline__ float g_of(int i) {
    // g_i = 2*C(2i,i)/4^i. Exact for i<8; 4-term Stirling beyond (rel<1e-7).
    const float fi = (float)i;
    float r = 2.0f * rsqrtf(3.14159265358979f * fi);
    float inv = 1.0f / fi;
    float corr = 1.0f + inv * (-0.125f + inv * (0.0078125f + inv * 0.0048828125f));
    float g = r * corr;
    if (i < 8) {
        const float gtab[8] = {2.0f, 1.0f, 0.75f, 0.625f, 0.546875f,
                               0.4921875f, 0.451171875f, 0.4189453125f};
        g = gtab[i];
    }
    return g;
}

__device__ __forceinline__ float wp_of(int i, const float* __restrict__ coef) {
    if (i > 256) return 0.0f;  // pad degree 257
    float fi = (float)i;
    return coef[i - 1] * sqrtf(2.0f * fi + 3.0f - 2.0f) * g_of(i);  // sqrt(2i+1)
}

// Pre-kernel: tab[m] = {beta(2m+1), w'(2m+2), beta(2m+2), w'(2m+3)},
// m = 0..127, plus a zero pad entry at m=128 for the prefetch.
__global__ __launch_bounds__(256) void build_tab(
    const float* __restrict__ coef, float4* __restrict__ tab)
{
    const int m = threadIdx.x;
    if (m < NPAIR) {
        const float d1 = 2.0f * (float)m + 1.0f;
        const float d2 = d1 + 1.0f;
        const float b1 = 4.0f * d1 * d1 / (4.0f * d1 * d1 - 1.0f);
        const float b2 = 4.0f * d2 * d2 / (4.0f * d2 * d2 - 1.0f);
        tab[m] = make_float4(b1, wp_of(2 * m + 2, coef),
                             b2, wp_of(2 * m + 3, coef));
    } else if (m == NPAIR) {
        tab[NPAIR] = make_float4(0.0f, 0.0f, 0.0f, 0.0f);
    }
}

__global__ __launch_bounds__(256, 8) void hippo_main(
    const float* __restrict__ t,
    const float* __restrict__ coef,
    const int* __restrict__ curr_t,
    const float4* __restrict__ tab,
    float* __restrict__ out,
    int n)
{
    const int gid = blockIdx.x * 256 + threadIdx.x;
    if (gid >= n) return;

    const float s = 2.0f / (float)curr_t[0];
    const float x = fmaf(t[gid], s, -1.0f);   // x = 2t/curr_t - 1
    const float X = 2.0f * x;

    float Sm1 = 0.5f;                          // S_0
    float S   = x;                             // S_1
    float acc = (coef[0] * 1.7320508075688772f) * x;  // w'_1 * S_1

    // Force wave-uniform address -> scalar s_load on the constant pipe.
    float4 c = tab[__builtin_amdgcn_readfirstlane(0)];
#pragma unroll 2
    for (int m = 0; m < NPAIR; ++m) {
        float4 cn = tab[__builtin_amdgcn_readfirstlane(m + 1)];  // prefetch
        // degree 2m+2
        float t1  = c.x * Sm1;
        float sn1 = fmaf(X, S, -t1);
        acc = fmaf(c.y, sn1, acc);
        // degree 2m+3 (t2 independent of sn1 -> short critical path)
        float t2  = c.z * S;
        float sn2 = fmaf(X, sn1, -t2);
        acc = fmaf(c.w, sn2, acc);
        Sm1 = sn1;
        S   = sn2;
        c   = cn;
    }

    out[gid] = acc;
}

extern "C" void kernel_launch(void* const* d_in, const int* in_sizes, int n_in,
                              void* d_out, int out_size, void* d_ws, size_t ws_size,
                              hipStream_t stream)
{
    const float* t      = (const float*)d_in[0];
    const float* coef   = (const float*)d_in[1];
    const int*   curr_t = (const int*)d_in[2];
    float*       out    = (float*)d_out;
    float4*      tab    = (float4*)d_ws;   // 129 * 16 B = 2064 B of scratch

    int n = in_sizes[0];                   // 524288
    build_tab<<<1, 256, 0, stream>>>(coef, tab);
    int blocks = (n + 255) / 256;          // 2048 blocks -> 8 blocks/CU
    hippo_main<<<blocks, 256, 0, stream>>>(t, coef, curr_t, tab, out, n);
}

// Round 4
// 65.424 us; speedup vs baseline: 1.1816x; 1.1816x over previous
//
#include <hip/hip_runtime.h>

// HiPPO-LegS reconstruction: out = sum_{i=1..256} coef[i-1]*sqrt(2i+1)*P_i(x),
// x = 2t/curr_t - 1.
//
// R1: 36KB unroll -> I$ thrash (~26us kernel). R2: LDS table in loop ->
// latency-bound (~26us). R3: 2-kernel + s_load-in-loop -> worse (+9us).
// R4: NO memory ops in the recurrence at all.
//   Q_i = sqrt(2i+1)*P_i  =>  Q_{i+1} = A_i*x*Q_i - B_i*Q_{i-1}
//   A_i = (2i+1)sqrt(2i+3)/((i+1)sqrt(2i+1)),  B_i = i*sqrt(2i+3)/((i+1)sqrt(2i-1))
// A_i,B_i are compile-time literals (constexpr sqrt); weights are plain
// coef[i] read as batched scalar loads (uniform address, constant offset).
// Full template unroll: 255 * 4 instr * ~7B ~= 7KB straight-line, I$-resident.
// 1 elem/thread, 2048 blocks -> 8 waves/SIMD: cross-wave interleave saturates
// the issue pipe despite the serial per-thread chain.
// VALU floor: 524288*255*4/32768 lanes-per-cyc = 16.3k cyc ~= 6.8us.

constexpr double csqrt(double v) {
    double r = v > 1.0 ? v : 1.0;
    for (int i = 0; i < 64; ++i) r = 0.5 * (r + v / r);
    return r;
}

template <int I>
struct Step {
    static __device__ __forceinline__ void run(const float x, float& qm1,
                                               float& q, float& acc,
                                               const float* __restrict__ coef) {
        constexpr float A = (float)((2.0 * I + 1.0) * csqrt(2.0 * I + 3.0) /
                                    ((I + 1.0) * csqrt(2.0 * I + 1.0)));
        constexpr float B = (float)((double)I * csqrt(2.0 * I + 3.0) /
                                    ((I + 1.0) * csqrt(2.0 * I - 1.0)));
        // Q_{I+1} = A*x*Q_I - B*Q_{I-1}   (mul-lit, mul-lit, fma with -mod)
        float u  = A * q;
        float v  = B * qm1;
        float qn = fmaf(x, u, -v);
        // weighted accumulate: v_fmac acc, s[coef_I], qn  (SGPR source)
        acc = fmaf(coef[I], qn, acc);
        qm1 = q;
        q   = qn;
        Step<I + 1>::run(x, qm1, q, acc, coef);
    }
};
template <>
struct Step<256> {
    static __device__ __forceinline__ void run(float, float&, float&, float&,
                                               const float*) {}
};

__global__ __launch_bounds__(256, 8) void hippo_kernel(
    const float* __restrict__ t,
    const float* __restrict__ coef,
    const int* __restrict__ curr_t,
    float* __restrict__ out,
    int n)
{
    const int gid = blockIdx.x * 256 + threadIdx.x;
    if (gid >= n) return;

    const float s = 2.0f / (float)curr_t[0];
    const float x = fmaf(t[gid], s, -1.0f);       // x = 2t/curr_t - 1

    float qm1 = 1.0f;                              // Q_0 = P_0
    float q   = 1.7320508075688772f * x;           // Q_1 = sqrt(3)*x
    float acc = coef[0] * q;                       // degree-1 term

    Step<1>::run(x, qm1, q, acc, coef);            // degrees 2..256

    out[gid] = acc;
}

extern "C" void kernel_launch(void* const* d_in, const int* in_sizes, int n_in,
                              void* d_out, int out_size, void* d_ws, size_t ws_size,
                              hipStream_t stream)
{
    const float* t      = (const float*)d_in[0];
    const float* coef   = (const float*)d_in[1];
    const int*   curr_t = (const int*)d_in[2];
    float*       out    = (float*)d_out;

    int n = in_sizes[0];                 // 524288
    int blocks = (n + 255) / 256;        // 2048 blocks -> 8 blocks/CU
    hippo_kernel<<<blocks, 256, 0, stream>>>(t, coef, curr_t, out, n);
}